// Round 1
// baseline (208.617 us; speedup 1.0000x reference)
//
#include <hip/hip_runtime.h>

typedef __attribute__((ext_vector_type(4))) float  f32x4;
typedef __attribute__((ext_vector_type(8))) short  bf16x8;
typedef __attribute__((ext_vector_type(8))) unsigned short u16x8;

#define NB 16      // batch
#define NN 2048    // nodes
#define FF 64      // features

// round-to-nearest-even f32 -> bf16 bits
__device__ __forceinline__ unsigned short f2bf(float x) {
  union { float f; unsigned int u; } c; c.f = x;
  unsigned int u = c.u;
  return (unsigned short)((u + 0x7fffu + ((u >> 16) & 1u)) >> 16);
}

__device__ __forceinline__ void gload16(const void* g, void* l) {
  __builtin_amdgcn_global_load_lds(
      (const __attribute__((address_space(1))) void*)g,
      (__attribute__((address_space(3))) void*)l, 16, 0, 0);
}

// Pass 1: rowsum (diag excluded, f32 exact) -> d = 1/(eps+sqrt(s)); A -> bf16 with diag zeroed.
__global__ __launch_bounds__(256) void rowsum_conv_kernel(
    const float* __restrict__ A, unsigned short* __restrict__ Abf,
    float* __restrict__ dvec) {
  int row = blockIdx.x;              // 0 .. NB*NN-1
  int i = row & (NN - 1);
  int tid = threadIdx.x;
  const float* arow = A + (size_t)row * NN;
  f32x4 v0 = *(const f32x4*)(arow + tid * 8);
  f32x4 v1 = *(const f32x4*)(arow + tid * 8 + 4);
  float vals[8] = {v0[0], v0[1], v0[2], v0[3], v1[0], v1[1], v1[2], v1[3]};
  float s = 0.f;
  u16x8 o;
#pragma unroll
  for (int jj = 0; jj < 8; ++jj) {
    int j = tid * 8 + jj;
    float v = (j == i) ? 0.f : vals[jj];
    s += v;
    o[jj] = f2bf(v);
  }
  *(u16x8*)(Abf + (size_t)row * NN + tid * 8) = o;
#pragma unroll
  for (int off = 32; off > 0; off >>= 1) s += __shfl_down(s, off, 64);
  __shared__ float red[4];
  if ((tid & 63) == 0) red[tid >> 6] = s;
  __syncthreads();
  if (tid == 0) {
    float t = red[0] + red[1] + red[2] + red[3];
    dvec[row] = 1.0f / (1e-6f + sqrtf(t));
  }
}

// U^T[b][f][n] = bf16(d[b][n] * V[b][n][f])  (transposed for MFMA B-operand)
// optionally Tb[b][n][f] = bf16(V) (unscaled, for final GEMM)
__global__ __launch_bounds__(256) void scale_transpose_kernel(
    const float* __restrict__ V, const float* __restrict__ dvec,
    unsigned short* __restrict__ UT, unsigned short* __restrict__ Tb) {
  int bid = blockIdx.x;
  int b = bid >> 5;
  int n0 = (bid & 31) * 64;
  int tid = threadIdx.x;
  __shared__ float t[64][65];
#pragma unroll
  for (int it = 0; it < 16; ++it) {
    int idx = tid + it * 256;
    int nl = idx >> 6, f = idx & 63;
    int n = n0 + nl;
    float v = V[((size_t)b * NN + n) * FF + f];
    if (Tb) Tb[((size_t)b * NN + n) * FF + f] = f2bf(v);
    t[f][nl] = v * dvec[b * NN + n];
  }
  __syncthreads();
#pragma unroll
  for (int it = 0; it < 16; ++it) {
    int idx = tid + it * 256;
    int f = idx >> 6, nl = idx & 63;
    UT[((size_t)b * FF + f) * NN + n0 + nl] = f2bf(t[f][nl]);
  }
}

// C = A_bf16[b] (64 rows x 2048) @ U (2048 x 64); epilogue:
//   v = cscale * d[n] * C[n][f] - prev[n][f];  Tout=f32(v) (opt), Tbout=bf16(v)
// BM=64, BK=64, 4 waves (2x2), wave tile 32x32. Double-buffered LDS,
// global_load_lds width-16, XOR swizzle (G4 / rule #21: linear dest +
// inverse-swizzled source + swizzled ds_read).
__global__ __launch_bounds__(256) void cheb_mm_kernel(
    const unsigned short* __restrict__ Abf,
    const unsigned short* __restrict__ UT,
    const float* __restrict__ dvec,
    const float* __restrict__ prev,     // nullable
    float* __restrict__ Tout,           // nullable
    unsigned short* __restrict__ Tbout,
    float cscale) {
  __shared__ unsigned short lds[16384];   // A dbuf [0,8192), U dbuf [8192,16384) (ushorts)
  int bid = blockIdx.x;
  int b = bid >> 5;
  int tm = bid & 31;
  int tid = threadIdx.x;
  int lane = tid & 63;
  int w = tid >> 6;
  int wm = w >> 1, wn = w & 1;
  int lr = lane >> 3;          // row within 8-row chunk
  int gs = (lane & 7) ^ lr;    // inverse-swizzled source slot
  int r16 = lane & 15, kq = lane >> 4;

  const size_t abase = ((size_t)b * NN + (size_t)tm * 64) * NN;
  const size_t ubase = (size_t)b * FF * NN;

  f32x4 acc[2][2] = {};

  auto stage = [&](int buf, int kt) {
    int k0 = kt * 64;
#pragma unroll
    for (int i = 0; i < 2; ++i) {
      int chunk = w * 2 + i;
      int r = chunk * 8 + lr;
      gload16(Abf + abase + (size_t)r * NN + k0 + gs * 8,
              &lds[buf * 4096 + chunk * 512]);
    }
#pragma unroll
    for (int i = 0; i < 2; ++i) {
      int chunk = w * 2 + i;
      int f = chunk * 8 + lr;
      gload16(UT + ubase + (size_t)f * NN + k0 + gs * 8,
              &lds[8192 + buf * 4096 + chunk * 512]);
    }
  };

  stage(0, 0);
  int cur = 0;
  for (int kt = 0; kt < NN / 64; ++kt) {
    __syncthreads();             // drains vmcnt: staged data ready, prev reads done
    if (kt + 1 < NN / 64) stage(cur ^ 1, kt + 1);
    bf16x8 af[2][2], bfr[2][2];
#pragma unroll
    for (int ks = 0; ks < 2; ++ks) {
#pragma unroll
      for (int mi = 0; mi < 2; ++mi) {
        int row = wm * 32 + mi * 16 + r16;
        af[mi][ks] = *(const bf16x8*)&lds[cur * 4096 + row * 64 +
                                          (((ks * 4 + kq) ^ (row & 7)) * 8)];
      }
#pragma unroll
      for (int ni = 0; ni < 2; ++ni) {
        int fr = wn * 32 + ni * 16 + r16;
        bfr[ni][ks] = *(const bf16x8*)&lds[8192 + cur * 4096 + fr * 64 +
                                           (((ks * 4 + kq) ^ (fr & 7)) * 8)];
      }
    }
#pragma unroll
    for (int ks = 0; ks < 2; ++ks)
#pragma unroll
      for (int mi = 0; mi < 2; ++mi)
#pragma unroll
        for (int ni = 0; ni < 2; ++ni)
          acc[mi][ni] = __builtin_amdgcn_mfma_f32_16x16x32_bf16(
              af[mi][ks], bfr[ni][ks], acc[mi][ni], 0, 0, 0);
    cur ^= 1;
  }

  // epilogue: D mapping col=lane&15, row=(lane>>4)*4+r  [m89-verified]
#pragma unroll
  for (int mi = 0; mi < 2; ++mi) {
#pragma unroll
    for (int r = 0; r < 4; ++r) {
      int row = tm * 64 + wm * 32 + mi * 16 + kq * 4 + r;
      float dv = dvec[b * NN + row] * cscale;
#pragma unroll
      for (int ni = 0; ni < 2; ++ni) {
        int col = wn * 32 + ni * 16 + r16;
        size_t idx = ((size_t)b * NN + row) * FF + col;
        float v = dv * acc[mi][ni][r];
        if (prev) v -= prev[idx];
        if (Tout) Tout[idx] = v;
        Tbout[idx] = f2bf(v);
      }
    }
  }
}

// kernel [256][128] f32 -> W^T [128][256] bf16
__global__ __launch_bounds__(256) void wt_conv_kernel(
    const float* __restrict__ Kr, unsigned short* __restrict__ WT) {
  int idx = blockIdx.x * 256 + threadIdx.x;   // < 32768
  int k = idx >> 7, c = idx & 127;
  WT[c * 256 + k] = f2bf(Kr[idx]);
}

// out[m][c] = relu( sum_k Z[m][k] * W[k][c] + bias[c] ),  Z = [Tb0|Tb1|Tb2|Tb3]
// BM=128, BN=128, BK=64 (one Tb slab per k-step), 4 waves 2x2, wave tile 64x64.
__global__ __launch_bounds__(256) void final_gemm_kernel(
    const unsigned short* __restrict__ Tb,   // [4][M][64] bf16
    const unsigned short* __restrict__ WT,   // [128][256] bf16
    const float* __restrict__ bias,
    float* __restrict__ out) {
  __shared__ unsigned short lds[32768];   // A dbuf [0,16384), B dbuf [16384,32768)
  const int M = NB * NN;
  int m0 = blockIdx.x * 128;
  int tid = threadIdx.x;
  int lane = tid & 63, w = tid >> 6;
  int wm = w >> 1, wn = w & 1;
  int lr = lane >> 3, gs = (lane & 7) ^ lr;
  int r16 = lane & 15, kq = lane >> 4;

  f32x4 acc[4][4] = {};

  auto stage = [&](int buf, int kt) {
    const unsigned short* asrc = Tb + (size_t)kt * M * FF;
#pragma unroll
    for (int i = 0; i < 4; ++i) {
      int chunk = w * 4 + i;
      int r = chunk * 8 + lr;
      gload16(asrc + (size_t)(m0 + r) * FF + gs * 8,
              &lds[buf * 8192 + chunk * 512]);
    }
#pragma unroll
    for (int i = 0; i < 4; ++i) {
      int chunk = w * 4 + i;
      int c = chunk * 8 + lr;
      gload16(WT + c * 256 + kt * 64 + gs * 8,
              &lds[16384 + buf * 8192 + chunk * 512]);
    }
  };

  stage(0, 0);
  int cur = 0;
  for (int kt = 0; kt < 4; ++kt) {
    __syncthreads();
    if (kt + 1 < 4) stage(cur ^ 1, kt + 1);
    bf16x8 af[4][2], bfr[4][2];
#pragma unroll
    for (int ks = 0; ks < 2; ++ks) {
#pragma unroll
      for (int mi = 0; mi < 4; ++mi) {
        int row = wm * 64 + mi * 16 + r16;
        af[mi][ks] = *(const bf16x8*)&lds[cur * 8192 + row * 64 +
                                          (((ks * 4 + kq) ^ (row & 7)) * 8)];
      }
#pragma unroll
      for (int ni = 0; ni < 4; ++ni) {
        int fr = wn * 64 + ni * 16 + r16;
        bfr[ni][ks] = *(const bf16x8*)&lds[16384 + cur * 8192 + fr * 64 +
                                           (((ks * 4 + kq) ^ (fr & 7)) * 8)];
      }
    }
#pragma unroll
    for (int ks = 0; ks < 2; ++ks)
#pragma unroll
      for (int mi = 0; mi < 4; ++mi)
#pragma unroll
        for (int ni = 0; ni < 4; ++ni)
          acc[mi][ni] = __builtin_amdgcn_mfma_f32_16x16x32_bf16(
              af[mi][ks], bfr[ni][ks], acc[mi][ni], 0, 0, 0);
    cur ^= 1;
  }

#pragma unroll
  for (int mi = 0; mi < 4; ++mi) {
#pragma unroll
    for (int r = 0; r < 4; ++r) {
      int row = m0 + wm * 64 + mi * 16 + kq * 4 + r;
#pragma unroll
      for (int ni = 0; ni < 4; ++ni) {
        int col = wn * 64 + ni * 16 + r16;
        float v = acc[mi][ni][r] + bias[col];
        out[(size_t)row * 128 + col] = v > 0.f ? v : 0.f;
      }
    }
  }
}

extern "C" void kernel_launch(void* const* d_in, const int* in_sizes, int n_in,
                              void* d_out, int out_size, void* d_ws, size_t ws_size,
                              hipStream_t stream) {
  const float* X    = (const float*)d_in[0];   // [16,2048,64]
  const float* A    = (const float*)d_in[1];   // [16,2048,2048]
  const float* Kr   = (const float*)d_in[2];   // [256,128]
  const float* bias = (const float*)d_in[3];   // [128]
  float* out = (float*)d_out;
  char* ws = (char*)d_ws;

  const size_t SZ_ABF = (size_t)NB * NN * NN * 2;   // 134 MB  A bf16
  const size_t SZ_D   = (size_t)NB * NN * 4;        // d vector
  const size_t SZ_UT  = (size_t)NB * FF * NN * 2;   // U^T bf16
  const size_t SZ_T   = (size_t)NB * NN * FF * 4;   // T f32
  const size_t SZ_TB  = (size_t)NB * NN * FF * 2;   // T bf16
  const size_t TBE    = (size_t)NB * NN * FF;       // elements per Tb slab

  unsigned short* Abf = (unsigned short*)ws;
  float*          dv  = (float*)(ws + SZ_ABF);
  unsigned short* UT  = (unsigned short*)(ws + SZ_ABF + SZ_D);
  float*          T1  = (float*)(ws + SZ_ABF + SZ_D + SZ_UT);
  float*          T2  = (float*)(ws + SZ_ABF + SZ_D + SZ_UT + SZ_T);
  unsigned short* Tb  = (unsigned short*)(ws + SZ_ABF + SZ_D + SZ_UT + 2 * SZ_T);
  unsigned short* WT  = (unsigned short*)(ws + SZ_ABF + SZ_D + SZ_UT + 2 * SZ_T + 4 * SZ_TB);

  rowsum_conv_kernel<<<NB * NN, 256, 0, stream>>>(A, Abf, dv);
  wt_conv_kernel<<<128, 256, 0, stream>>>(Kr, WT);
  // T0 = X: U = bf16(d*X), Tb0 = bf16(X)
  scale_transpose_kernel<<<512, 256, 0, stream>>>(X, dv, UT, Tb);
  // T1 = d ⊙ (A @ U0)
  cheb_mm_kernel<<<512, 256, 0, stream>>>(Abf, UT, dv, nullptr, T1, Tb + TBE, 1.0f);
  scale_transpose_kernel<<<512, 256, 0, stream>>>(T1, dv, UT, nullptr);
  // T2 = 2 d ⊙ (A @ U1) - X
  cheb_mm_kernel<<<512, 256, 0, stream>>>(Abf, UT, dv, X, T2, Tb + 2 * TBE, 2.0f);
  scale_transpose_kernel<<<512, 256, 0, stream>>>(T2, dv, UT, nullptr);
  // T3 = 2 d ⊙ (A @ U2) - T1  (f32 copy not needed)
  cheb_mm_kernel<<<512, 256, 0, stream>>>(Abf, UT, dv, T1, nullptr, Tb + 3 * TBE, 2.0f);
  final_gemm_kernel<<<256, 256, 0, stream>>>(Tb, WT, bias, out);
}

// Round 2
// 185.201 us; speedup vs baseline: 1.1264x; 1.1264x over previous
//
#include <hip/hip_runtime.h>

typedef __attribute__((ext_vector_type(4))) float  f32x4;
typedef __attribute__((ext_vector_type(8))) short  bf16x8;
typedef __attribute__((ext_vector_type(8))) unsigned short u16x8;
typedef __attribute__((ext_vector_type(4))) unsigned short u16x4;

#define NB 16      // batch
#define NN 2048    // nodes
#define FF 64      // features

// round-to-nearest-even f32 -> bf16 bits
__device__ __forceinline__ unsigned short f2bf(float x) {
  union { float f; unsigned int u; } c; c.f = x;
  unsigned int u = c.u;
  return (unsigned short)((u + 0x7fffu + ((u >> 16) & 1u)) >> 16);
}
__device__ __forceinline__ float bf2f(unsigned short b) {
  union { unsigned int u; float f; } c; c.u = (unsigned int)b << 16;
  return c.f;
}

__device__ __forceinline__ void gload16(const void* g, void* l) {
  __builtin_amdgcn_global_load_lds(
      (const __attribute__((address_space(1))) void*)g,
      (__attribute__((address_space(3))) void*)l, 16, 0, 0);
}

#define BAR() asm volatile("s_barrier" ::: "memory")

// Pass 1: one wave per row. rowsum (diag excluded, f32) -> d = 1/(eps+sqrt(s));
// A -> bf16 with diag zeroed. No LDS, no __syncthreads.
__global__ __launch_bounds__(256) void rowsum_conv_kernel(
    const float* __restrict__ A, unsigned short* __restrict__ Abf,
    float* __restrict__ dvec) {
  int row = blockIdx.x * 4 + (threadIdx.x >> 6);
  int lane = threadIdx.x & 63;
  int i = row & (NN - 1);
  const float* arow = A + (size_t)row * NN;
  unsigned short* orow = Abf + (size_t)row * NN;
  float s = 0.f;
#pragma unroll
  for (int p = 0; p < 8; ++p) {
    int base = p * 256 + lane * 4;
    f32x4 v = *(const f32x4*)(arow + base);
    u16x4 o;
#pragma unroll
    for (int jj = 0; jj < 4; ++jj) {
      float x = (base + jj == i) ? 0.f : v[jj];
      s += x;
      o[jj] = f2bf(x);
    }
    *(u16x4*)(orow + base) = o;
  }
#pragma unroll
  for (int off = 32; off > 0; off >>= 1) s += __shfl_down(s, off, 64);
  if (lane == 0) dvec[row] = 1.0f / (1e-6f + sqrtf(s));
}

// U^T[b][f][n] = bf16(d[b][n] * V[b][n][f]); Tb[b][n][f] = bf16(V). (for X only)
__global__ __launch_bounds__(256) void scale_transpose_kernel(
    const float* __restrict__ V, const float* __restrict__ dvec,
    unsigned short* __restrict__ UT, unsigned short* __restrict__ Tb) {
  int bid = blockIdx.x;
  int b = bid >> 5;
  int n0 = (bid & 31) * 64;
  int tid = threadIdx.x;
  __shared__ float t[64][65];
#pragma unroll
  for (int it = 0; it < 16; ++it) {
    int idx = tid + it * 256;
    int nl = idx >> 6, f = idx & 63;
    int n = n0 + nl;
    float v = V[((size_t)b * NN + n) * FF + f];
    if (Tb) Tb[((size_t)b * NN + n) * FF + f] = f2bf(v);
    t[f][nl] = v * dvec[b * NN + n];
  }
  __syncthreads();
#pragma unroll
  for (int it = 0; it < 16; ++it) {
    int idx = tid + it * 256;
    int f = idx >> 6, nl = idx & 63;
    UT[((size_t)b * FF + f) * NN + n0 + nl] = f2bf(t[f][nl]);
  }
}

// C = A_bf16[b] (64 rows x 2048) @ U (2048 x 64); epilogue:
//   v = cscale * d[n] * C[n][f] - prevb[n][f](bf16)
//   Tbout = bf16(v) row-major; UTout = bf16(d[n]*v) transposed (via LDS).
// 3-deep LDS pipeline, counted vmcnt (never 0 in steady state), raw s_barrier.
__global__ __launch_bounds__(256) void cheb_mm_kernel(
    const unsigned short* __restrict__ Abf,
    const unsigned short* __restrict__ UT,
    const float* __restrict__ dvec,
    const unsigned short* __restrict__ prevb,   // nullable
    unsigned short* __restrict__ Tbout,
    unsigned short* __restrict__ UTout,         // nullable
    float cscale) {
  __shared__ unsigned short lds[24576];   // A: 3 x 4096 at 0; U: 3 x 4096 at 12288
  int bid = blockIdx.x;
  int b = bid >> 5;
  int tm = bid & 31;
  int tid = threadIdx.x;
  int lane = tid & 63;
  int w = tid >> 6;
  int wm = w >> 1, wn = w & 1;
  int lr = lane >> 3;          // row within 8-row chunk
  int gs = (lane & 7) ^ lr;    // inverse-swizzled source slot
  int r16 = lane & 15, kq = lane >> 4;
  const int NT = NN / 64;      // 32 k-steps

  const size_t abase = ((size_t)b * NN + (size_t)tm * 64) * NN;
  const size_t ubase = (size_t)b * FF * NN;

  f32x4 acc[2][2] = {};

  auto stage = [&](int s, int kt) {   // 4 gload16 per wave
    int k0 = kt * 64;
#pragma unroll
    for (int i = 0; i < 2; ++i) {
      int chunk = w * 2 + i;
      int r = chunk * 8 + lr;
      gload16(Abf + abase + (size_t)r * NN + k0 + gs * 8,
              &lds[s * 4096 + chunk * 512]);
    }
#pragma unroll
    for (int i = 0; i < 2; ++i) {
      int chunk = w * 2 + i;
      int f = chunk * 8 + lr;
      gload16(UT + ubase + (size_t)f * NN + k0 + gs * 8,
              &lds[12288 + s * 4096 + chunk * 512]);
    }
  };

  stage(0, 0); stage(1, 1); stage(2, 2);
  for (int t = 0; t < NT; ++t) {
    int s = t % 3;
    int rem = NT - 1 - t;
    if (rem >= 2)      asm volatile("s_waitcnt vmcnt(8)" ::: "memory");
    else if (rem == 1) asm volatile("s_waitcnt vmcnt(4)" ::: "memory");
    else               asm volatile("s_waitcnt vmcnt(0)" ::: "memory");
    BAR();                                  // buf s ready for all waves
    bf16x8 af[2][2], bfr[2][2];
#pragma unroll
    for (int ks = 0; ks < 2; ++ks) {
#pragma unroll
      for (int mi = 0; mi < 2; ++mi) {
        int row = wm * 32 + mi * 16 + r16;
        af[mi][ks] = *(const bf16x8*)&lds[s * 4096 + row * 64 +
                                          (((ks * 4 + kq) ^ (row & 7)) * 8)];
      }
#pragma unroll
      for (int ni = 0; ni < 2; ++ni) {
        int fr = wn * 32 + ni * 16 + r16;
        bfr[ni][ks] = *(const bf16x8*)&lds[12288 + s * 4096 + fr * 64 +
                                           (((ks * 4 + kq) ^ (fr & 7)) * 8)];
      }
    }
#pragma unroll
    for (int ks = 0; ks < 2; ++ks)
#pragma unroll
      for (int mi = 0; mi < 2; ++mi)
#pragma unroll
        for (int ni = 0; ni < 2; ++ni)
          acc[mi][ni] = __builtin_amdgcn_mfma_f32_16x16x32_bf16(
              af[mi][ks], bfr[ni][ks], acc[mi][ni], 0, 0, 0);
    BAR();                                  // all waves done reading buf s
    if (t + 3 < NT) stage(s, t + 3);
  }

  // epilogue: D mapping col=lane&15, row=(lane>>4)*4+r  [m89-verified]
  unsigned short (*tl)[72] = (unsigned short(*)[72])lds;  // 64x72 = 9216 ushorts
  int n0 = tm * 64;
#pragma unroll
  for (int mi = 0; mi < 2; ++mi) {
#pragma unroll
    for (int r = 0; r < 4; ++r) {
      int rl = wm * 32 + mi * 16 + kq * 4 + r;
      int row = n0 + rl;
      float dd = dvec[b * NN + row];
      float dc = dd * cscale;
#pragma unroll
      for (int ni = 0; ni < 2; ++ni) {
        int col = wn * 32 + ni * 16 + r16;
        size_t idx = ((size_t)b * NN + row) * FF + col;
        float v = dc * acc[mi][ni][r];
        if (prevb) v -= bf2f(prevb[idx]);
        Tbout[idx] = f2bf(v);
        if (UTout) tl[col][rl] = f2bf(dd * v);
      }
    }
  }
  if (UTout) {
    __syncthreads();
#pragma unroll
    for (int it = 0; it < 2; ++it) {
      int c = tid + it * 256;
      int f = c >> 3, nl0 = (c & 7) * 8;
      u16x8 vv = *(const u16x8*)&tl[f][nl0];
      *(u16x8*)&UTout[((size_t)b * FF + f) * NN + n0 + nl0] = vv;
    }
  }
}

// kernel [256][128] f32 -> W^T [128][256] bf16
__global__ __launch_bounds__(256) void wt_conv_kernel(
    const float* __restrict__ Kr, unsigned short* __restrict__ WT) {
  int idx = blockIdx.x * 256 + threadIdx.x;   // < 32768
  int k = idx >> 7, c = idx & 127;
  WT[c * 256 + k] = f2bf(Kr[idx]);
}

// out[m][c] = relu( sum_k Z[m][k]*W[k][c] + bias[c] ), Z = [Tb0|Tb1|Tb2|Tb3]
// BM=64, BN=128, BK=64; 4 waves (2x2), wave tile 32x64; 3-deep counted-vmcnt.
__global__ __launch_bounds__(256) void final_gemm_kernel(
    const unsigned short* __restrict__ Tb,   // [4][M][64] bf16
    const unsigned short* __restrict__ WT,   // [128][256] bf16
    const float* __restrict__ bias,
    float* __restrict__ out) {
  __shared__ unsigned short lds[36864];   // A: 3 x 4096 at 0; B: 3 x 8192 at 12288
  const int M = NB * NN;
  int m0 = blockIdx.x * 64;
  int tid = threadIdx.x;
  int lane = tid & 63, w = tid >> 6;
  int wm = w >> 1, wn = w & 1;
  int lr = lane >> 3, gs = (lane & 7) ^ lr;
  int r16 = lane & 15, kq = lane >> 4;

  f32x4 acc[2][4] = {};

  auto stage = [&](int s, int kt) {   // 6 gload16 per wave
    const unsigned short* asrc = Tb + (size_t)kt * M * FF;
#pragma unroll
    for (int i = 0; i < 2; ++i) {
      int chunk = w * 2 + i;                   // 8 chunks: 64 rows
      int r = chunk * 8 + lr;
      gload16(asrc + (size_t)(m0 + r) * FF + gs * 8,
              &lds[s * 4096 + chunk * 512]);
    }
#pragma unroll
    for (int i = 0; i < 4; ++i) {
      int chunk = w * 4 + i;                   // 16 chunks: 128 c-rows
      int c = chunk * 8 + lr;
      gload16(WT + c * 256 + kt * 64 + gs * 8,
              &lds[12288 + s * 8192 + chunk * 512]);
    }
  };

  stage(0, 0); stage(1, 1); stage(2, 2);
  for (int t = 0; t < 4; ++t) {
    int s = t % 3;
    int rem = 3 - t;
    if (rem >= 2)      asm volatile("s_waitcnt vmcnt(12)" ::: "memory");
    else if (rem == 1) asm volatile("s_waitcnt vmcnt(6)" ::: "memory");
    else               asm volatile("s_waitcnt vmcnt(0)" ::: "memory");
    BAR();
    bf16x8 af[2][2], bfr[4][2];
#pragma unroll
    for (int ks = 0; ks < 2; ++ks) {
#pragma unroll
      for (int mi = 0; mi < 2; ++mi) {
        int row = wm * 32 + mi * 16 + r16;
        af[mi][ks] = *(const bf16x8*)&lds[s * 4096 + row * 64 +
                                          (((ks * 4 + kq) ^ (row & 7)) * 8)];
      }
#pragma unroll
      for (int ni = 0; ni < 4; ++ni) {
        int fr = wn * 64 + ni * 16 + r16;
        bfr[ni][ks] = *(const bf16x8*)&lds[12288 + s * 8192 + fr * 64 +
                                           (((ks * 4 + kq) ^ (fr & 7)) * 8)];
      }
    }
#pragma unroll
    for (int ks = 0; ks < 2; ++ks)
#pragma unroll
      for (int mi = 0; mi < 2; ++mi)
#pragma unroll
        for (int ni = 0; ni < 4; ++ni)
          acc[mi][ni] = __builtin_amdgcn_mfma_f32_16x16x32_bf16(
              af[mi][ks], bfr[ni][ks], acc[mi][ni], 0, 0, 0);
    BAR();
    if (t + 3 < 4) stage(s, t + 3);
  }

#pragma unroll
  for (int mi = 0; mi < 2; ++mi) {
#pragma unroll
    for (int r = 0; r < 4; ++r) {
      int row = m0 + wm * 32 + mi * 16 + kq * 4 + r;
#pragma unroll
      for (int ni = 0; ni < 4; ++ni) {
        int col = wn * 64 + ni * 16 + r16;
        float v = acc[mi][ni][r] + bias[col];
        out[(size_t)row * 128 + col] = v > 0.f ? v : 0.f;
      }
    }
  }
}

extern "C" void kernel_launch(void* const* d_in, const int* in_sizes, int n_in,
                              void* d_out, int out_size, void* d_ws, size_t ws_size,
                              hipStream_t stream) {
  const float* X    = (const float*)d_in[0];   // [16,2048,64]
  const float* A    = (const float*)d_in[1];   // [16,2048,2048]
  const float* Kr   = (const float*)d_in[2];   // [256,128]
  const float* bias = (const float*)d_in[3];   // [128]
  float* out = (float*)d_out;
  char* ws = (char*)d_ws;

  const size_t SZ_ABF = (size_t)NB * NN * NN * 2;   // 134 MB
  const size_t SZ_D   = (size_t)NB * NN * 4;
  const size_t SZ_UT  = (size_t)NB * FF * NN * 2;   // 4 MB
  const size_t SZ_TB  = (size_t)NB * NN * FF * 2;   // 4 MB per slab
  const size_t TBE    = (size_t)NB * NN * FF;       // elements per Tb slab

  unsigned short* Abf = (unsigned short*)ws;
  float*          dv  = (float*)(ws + SZ_ABF);
  unsigned short* UTa = (unsigned short*)(ws + SZ_ABF + SZ_D);
  unsigned short* UTb = (unsigned short*)(ws + SZ_ABF + SZ_D + SZ_UT);
  unsigned short* Tb  = (unsigned short*)(ws + SZ_ABF + SZ_D + 2 * SZ_UT);
  unsigned short* WT  = (unsigned short*)(ws + SZ_ABF + SZ_D + 2 * SZ_UT + 4 * SZ_TB);

  rowsum_conv_kernel<<<NB * NN / 4, 256, 0, stream>>>(A, Abf, dv);
  wt_conv_kernel<<<128, 256, 0, stream>>>(Kr, WT);
  // T0 = X: UTa = bf16(d*X), Tb0 = bf16(X)
  scale_transpose_kernel<<<512, 256, 0, stream>>>(X, dv, UTa, Tb);
  // T1 = d ⊙ (A @ U0);      Tb1, UTb = d*T1
  cheb_mm_kernel<<<512, 256, 0, stream>>>(Abf, UTa, dv, nullptr, Tb + TBE, UTb, 1.0f);
  // T2 = 2 d ⊙ (A @ U1) - T0;  Tb2, UTa = d*T2
  cheb_mm_kernel<<<512, 256, 0, stream>>>(Abf, UTb, dv, Tb, Tb + 2 * TBE, UTa, 2.0f);
  // T3 = 2 d ⊙ (A @ U2) - T1;  Tb3
  cheb_mm_kernel<<<512, 256, 0, stream>>>(Abf, UTa, dv, Tb + TBE, Tb + 3 * TBE, nullptr, 2.0f);
  final_gemm_kernel<<<512, 256, 0, stream>>>(Tb, WT, bias, out);
}

// Round 3
// 154.175 us; speedup vs baseline: 1.3531x; 1.2012x over previous
//
#include <hip/hip_runtime.h>

typedef __attribute__((ext_vector_type(4))) float  f32x4;
typedef __attribute__((ext_vector_type(8))) short  bf16x8;
typedef __attribute__((ext_vector_type(8))) unsigned short u16x8;
typedef __attribute__((ext_vector_type(4))) unsigned short u16x4;

#define NB 16      // batch
#define NN 2048    // nodes
#define FF 64      // features

// round-to-nearest-even f32 -> bf16 bits
__device__ __forceinline__ unsigned short f2bf(float x) {
  union { float f; unsigned int u; } c; c.f = x;
  unsigned int u = c.u;
  return (unsigned short)((u + 0x7fffu + ((u >> 16) & 1u)) >> 16);
}
__device__ __forceinline__ float bf2f(unsigned short b) {
  union { unsigned int u; float f; } c; c.u = (unsigned int)b << 16;
  return c.f;
}

__device__ __forceinline__ void gload16(const void* g, void* l) {
  __builtin_amdgcn_global_load_lds(
      (const __attribute__((address_space(1))) void*)g,
      (__attribute__((address_space(3))) void*)l, 16, 0, 0);
}

#define BAR() asm volatile("s_barrier" ::: "memory")

// Pass 1: one wave per row. rowsum (diag excluded, f32) -> d = 1/(eps+sqrt(s));
// A -> bf16 with diag zeroed. NT loads: A is read exactly once -> don't let it
// evict the freshly written Abf from L3 (cheb1 re-reads Abf immediately).
__global__ __launch_bounds__(256) void rowsum_conv_kernel(
    const float* __restrict__ A, unsigned short* __restrict__ Abf,
    float* __restrict__ dvec) {
  int row = blockIdx.x * 4 + (threadIdx.x >> 6);
  int lane = threadIdx.x & 63;
  int i = row & (NN - 1);
  const float* arow = A + (size_t)row * NN;
  unsigned short* orow = Abf + (size_t)row * NN;
  float s = 0.f;
#pragma unroll
  for (int p = 0; p < 8; ++p) {
    int base = p * 256 + lane * 4;
    f32x4 v = __builtin_nontemporal_load((const f32x4*)(arow + base));
    u16x4 o;
#pragma unroll
    for (int jj = 0; jj < 4; ++jj) {
      float x = (base + jj == i) ? 0.f : v[jj];
      s += x;
      o[jj] = f2bf(x);
    }
    *(u16x4*)(orow + base) = o;
  }
#pragma unroll
  for (int off = 32; off > 0; off >>= 1) s += __shfl_down(s, off, 64);
  if (lane == 0) dvec[row] = 1.0f / (1e-6f + sqrtf(s));
}

// blocks 0..511:  U^T[b][f][n] = bf16(d[b][n]*V[b][n][f]); Tb[b][n][f] = bf16(V)
// blocks 512..639: WT[c][k] = bf16(Kr[k][c])   (fused weight transpose)
__global__ __launch_bounds__(256) void scale_transpose_kernel(
    const float* __restrict__ V, const float* __restrict__ dvec,
    unsigned short* __restrict__ UT, unsigned short* __restrict__ Tb,
    const float* __restrict__ Kr, unsigned short* __restrict__ WT) {
  int bid = blockIdx.x;
  int tid = threadIdx.x;
  if (bid >= 512) {
    int idx = (bid - 512) * 256 + tid;     // < 32768
    int k = idx >> 7, c = idx & 127;
    WT[c * 256 + k] = f2bf(Kr[idx]);
    return;
  }
  int b = bid >> 5;
  int n0 = (bid & 31) * 64;
  __shared__ float t[64][65];
#pragma unroll
  for (int it = 0; it < 4; ++it) {
    int e = it * 256 + tid;                // 1024 groups of 4 elements
    int nl = e >> 4;
    int f0 = (e & 15) * 4;
    int n = n0 + nl;
    f32x4 v = *(const f32x4*)&V[((size_t)b * NN + n) * FF + f0];
    float dd = dvec[b * NN + n];
    u16x4 o;
#pragma unroll
    for (int j = 0; j < 4; ++j) { o[j] = f2bf(v[j]); t[f0 + j][nl] = v[j] * dd; }
    *(u16x4*)&Tb[((size_t)b * NN + n) * FF + f0] = o;
  }
  __syncthreads();
#pragma unroll
  for (int it = 0; it < 2; ++it) {
    int c = it * 256 + tid;                // 512 groups of 8
    int f = c >> 3, nl0 = (c & 7) * 8;
    u16x8 vv;
#pragma unroll
    for (int j = 0; j < 8; ++j) vv[j] = f2bf(t[f][nl0 + j]);
    *(u16x8*)&UT[((size_t)b * FF + f) * NN + n0 + nl0] = vv;
  }
}

// C = A_bf16[b] (64 rows x 2048) @ U (2048 x 64); epilogue:
//   v = cscale * d[n] * C[n][f] - prevb[n][f](bf16)
//   Tbout = bf16(v) row-major; UTout = bf16(d[n]*v) transposed (via LDS).
// 3-deep LDS pipeline, counted vmcnt (never 0 in steady state), raw s_barrier.
// XCD swizzle: blocks of batches {2x,2x+1} land on XCD x (round-robin bid%8)
// so the per-batch 256 KB UT panel stays L2-resident (512 KB/XCD vs 4 MB).
__global__ __launch_bounds__(256) void cheb_mm_kernel(
    const unsigned short* __restrict__ Abf,
    const unsigned short* __restrict__ UT,
    const float* __restrict__ dvec,
    const unsigned short* __restrict__ prevb,   // nullable
    unsigned short* __restrict__ Tbout,
    unsigned short* __restrict__ UTout,         // nullable
    float cscale) {
  __shared__ unsigned short lds[24576];   // A: 3 x 4096 at 0; U: 3 x 4096 at 12288
  int bid = blockIdx.x;
  int slot = bid >> 3;
  int b = (bid & 7) * 2 + (slot >> 5);
  int tm = slot & 31;
  int tid = threadIdx.x;
  int lane = tid & 63;
  int w = tid >> 6;
  int wm = w >> 1, wn = w & 1;
  int lr = lane >> 3;          // row within 8-row chunk
  int gs = (lane & 7) ^ lr;    // inverse-swizzled source slot
  int r16 = lane & 15, kq = lane >> 4;
  const int NT = NN / 64;      // 32 k-steps

  const size_t abase = ((size_t)b * NN + (size_t)tm * 64) * NN;
  const size_t ubase = (size_t)b * FF * NN;

  f32x4 acc[2][2] = {};

  auto stage = [&](int s, int kt) {   // 4 gload16 per wave
    int k0 = kt * 64;
#pragma unroll
    for (int i = 0; i < 2; ++i) {
      int chunk = w * 2 + i;
      int r = chunk * 8 + lr;
      gload16(Abf + abase + (size_t)r * NN + k0 + gs * 8,
              &lds[s * 4096 + chunk * 512]);
    }
#pragma unroll
    for (int i = 0; i < 2; ++i) {
      int chunk = w * 2 + i;
      int f = chunk * 8 + lr;
      gload16(UT + ubase + (size_t)f * NN + k0 + gs * 8,
              &lds[12288 + s * 4096 + chunk * 512]);
    }
  };

  stage(0, 0); stage(1, 1); stage(2, 2);
  int s = 0;
  for (int t = 0; t < NT; ++t) {
    if (t < NT - 2)       asm volatile("s_waitcnt vmcnt(8)" ::: "memory");
    else if (t == NT - 2) asm volatile("s_waitcnt vmcnt(4)" ::: "memory");
    else                  asm volatile("s_waitcnt vmcnt(0)" ::: "memory");
    BAR();                                  // buf s ready for all waves
    bf16x8 af[2][2], bfr[2][2];
#pragma unroll
    for (int ks = 0; ks < 2; ++ks) {
#pragma unroll
      for (int mi = 0; mi < 2; ++mi) {
        int row = wm * 32 + mi * 16 + r16;
        af[mi][ks] = *(const bf16x8*)&lds[s * 4096 + row * 64 +
                                          (((ks * 4 + kq) ^ (row & 7)) * 8)];
      }
#pragma unroll
      for (int ni = 0; ni < 2; ++ni) {
        int fr = wn * 32 + ni * 16 + r16;
        bfr[ni][ks] = *(const bf16x8*)&lds[12288 + s * 4096 + fr * 64 +
                                           (((ks * 4 + kq) ^ (fr & 7)) * 8)];
      }
    }
#pragma unroll
    for (int ks = 0; ks < 2; ++ks)
#pragma unroll
      for (int mi = 0; mi < 2; ++mi)
#pragma unroll
        for (int ni = 0; ni < 2; ++ni)
          acc[mi][ni] = __builtin_amdgcn_mfma_f32_16x16x32_bf16(
              af[mi][ks], bfr[ni][ks], acc[mi][ni], 0, 0, 0);
    BAR();                                  // all waves done reading buf s
    if (t + 3 < NT) stage(s, t + 3);
    s = (s == 2) ? 0 : s + 1;
  }

  // epilogue: D mapping col=lane&15, row=(lane>>4)*4+r  [m89-verified]
  unsigned short (*tl)[72] = (unsigned short(*)[72])lds;  // 64x72 = 9216 ushorts
  int n0 = tm * 64;
#pragma unroll
  for (int mi = 0; mi < 2; ++mi) {
#pragma unroll
    for (int r = 0; r < 4; ++r) {
      int rl = wm * 32 + mi * 16 + kq * 4 + r;
      int row = n0 + rl;
      float dd = dvec[b * NN + row];
      float dc = dd * cscale;
#pragma unroll
      for (int ni = 0; ni < 2; ++ni) {
        int col = wn * 32 + ni * 16 + r16;
        size_t idx = ((size_t)b * NN + row) * FF + col;
        float v = dc * acc[mi][ni][r];
        if (prevb) v -= bf2f(prevb[idx]);
        Tbout[idx] = f2bf(v);
        if (UTout) tl[col][rl] = f2bf(dd * v);
      }
    }
  }
  if (UTout) {
    __syncthreads();
#pragma unroll
    for (int it = 0; it < 2; ++it) {
      int c = tid + it * 256;
      int f = c >> 3, nl0 = (c & 7) * 8;
      u16x8 vv = *(const u16x8*)&tl[f][nl0];
      *(u16x8*)&UTout[((size_t)b * FF + f) * NN + n0 + nl0] = vv;
    }
  }
}

// out[m][c] = relu( sum_k Z[m][k]*W[k][c] + bias[c] ), Z = [Tb0|Tb1|Tb2|Tb3]
// BM=64, BN=128, BK=64; 4 waves (2x2), wave tile 32x64; 3-deep counted-vmcnt.
__global__ __launch_bounds__(256) void final_gemm_kernel(
    const unsigned short* __restrict__ Tb,   // [4][M][64] bf16
    const unsigned short* __restrict__ WT,   // [128][256] bf16
    const float* __restrict__ bias,
    float* __restrict__ out) {
  __shared__ unsigned short lds[36864];   // A: 3 x 4096 at 0; B: 3 x 8192 at 12288
  const int M = NB * NN;
  int m0 = blockIdx.x * 64;
  int tid = threadIdx.x;
  int lane = tid & 63, w = tid >> 6;
  int wm = w >> 1, wn = w & 1;
  int lr = lane >> 3, gs = (lane & 7) ^ lr;
  int r16 = lane & 15, kq = lane >> 4;

  f32x4 acc[2][4] = {};

  auto stage = [&](int s, int kt) {   // 6 gload16 per wave
    const unsigned short* asrc = Tb + (size_t)kt * M * FF;
#pragma unroll
    for (int i = 0; i < 2; ++i) {
      int chunk = w * 2 + i;                   // 8 chunks: 64 rows
      int r = chunk * 8 + lr;
      gload16(asrc + (size_t)(m0 + r) * FF + gs * 8,
              &lds[s * 4096 + chunk * 512]);
    }
#pragma unroll
    for (int i = 0; i < 4; ++i) {
      int chunk = w * 4 + i;                   // 16 chunks: 128 c-rows
      int c = chunk * 8 + lr;
      gload16(WT + c * 256 + kt * 64 + gs * 8,
              &lds[12288 + s * 8192 + chunk * 512]);
    }
  };

  stage(0, 0); stage(1, 1); stage(2, 2);
  int s = 0;
  for (int t = 0; t < 4; ++t) {
    if (t < 2)       asm volatile("s_waitcnt vmcnt(12)" ::: "memory");
    else if (t == 2) asm volatile("s_waitcnt vmcnt(6)" ::: "memory");
    else             asm volatile("s_waitcnt vmcnt(0)" ::: "memory");
    BAR();
    bf16x8 af[2][2], bfr[4][2];
#pragma unroll
    for (int ks = 0; ks < 2; ++ks) {
#pragma unroll
      for (int mi = 0; mi < 2; ++mi) {
        int row = wm * 32 + mi * 16 + r16;
        af[mi][ks] = *(const bf16x8*)&lds[s * 4096 + row * 64 +
                                          (((ks * 4 + kq) ^ (row & 7)) * 8)];
      }
#pragma unroll
      for (int ni = 0; ni < 4; ++ni) {
        int fr = wn * 64 + ni * 16 + r16;
        bfr[ni][ks] = *(const bf16x8*)&lds[12288 + s * 8192 + fr * 64 +
                                           (((ks * 4 + kq) ^ (fr & 7)) * 8)];
      }
    }
#pragma unroll
    for (int ks = 0; ks < 2; ++ks)
#pragma unroll
      for (int mi = 0; mi < 2; ++mi)
#pragma unroll
        for (int ni = 0; ni < 4; ++ni)
          acc[mi][ni] = __builtin_amdgcn_mfma_f32_16x16x32_bf16(
              af[mi][ks], bfr[ni][ks], acc[mi][ni], 0, 0, 0);
    BAR();
    if (t + 3 < 4) stage(s, t + 3);
    s = (s == 2) ? 0 : s + 1;
  }

#pragma unroll
  for (int mi = 0; mi < 2; ++mi) {
#pragma unroll
    for (int r = 0; r < 4; ++r) {
      int row = m0 + wm * 32 + mi * 16 + kq * 4 + r;
#pragma unroll
      for (int ni = 0; ni < 4; ++ni) {
        int col = wn * 64 + ni * 16 + r16;
        float v = acc[mi][ni][r] + bias[col];
        out[(size_t)row * 128 + col] = v > 0.f ? v : 0.f;
      }
    }
  }
}

extern "C" void kernel_launch(void* const* d_in, const int* in_sizes, int n_in,
                              void* d_out, int out_size, void* d_ws, size_t ws_size,
                              hipStream_t stream) {
  const float* X    = (const float*)d_in[0];   // [16,2048,64]
  const float* A    = (const float*)d_in[1];   // [16,2048,2048]
  const float* Kr   = (const float*)d_in[2];   // [256,128]
  const float* bias = (const float*)d_in[3];   // [128]
  float* out = (float*)d_out;
  char* ws = (char*)d_ws;

  const size_t SZ_ABF = (size_t)NB * NN * NN * 2;   // 134 MB
  const size_t SZ_D   = (size_t)NB * NN * 4;
  const size_t SZ_UT  = (size_t)NB * FF * NN * 2;   // 4 MB
  const size_t SZ_TB  = (size_t)NB * NN * FF * 2;   // 4 MB per slab
  const size_t TBE    = (size_t)NB * NN * FF;       // elements per Tb slab

  unsigned short* Abf = (unsigned short*)ws;
  float*          dv  = (float*)(ws + SZ_ABF);
  unsigned short* UTa = (unsigned short*)(ws + SZ_ABF + SZ_D);
  unsigned short* UTb = (unsigned short*)(ws + SZ_ABF + SZ_D + SZ_UT);
  unsigned short* Tb  = (unsigned short*)(ws + SZ_ABF + SZ_D + 2 * SZ_UT);
  unsigned short* WT  = (unsigned short*)(ws + SZ_ABF + SZ_D + 2 * SZ_UT + 4 * SZ_TB);

  rowsum_conv_kernel<<<NB * NN / 4, 256, 0, stream>>>(A, Abf, dv);
  // T0 = X: UTa = bf16(d*X), Tb0 = bf16(X); blocks 512+ convert the weight
  scale_transpose_kernel<<<640, 256, 0, stream>>>(X, dv, UTa, Tb, Kr, WT);
  // T1 = d ⊙ (A @ U0);      Tb1, UTb = d*T1
  cheb_mm_kernel<<<512, 256, 0, stream>>>(Abf, UTa, dv, nullptr, Tb + TBE, UTb, 1.0f);
  // T2 = 2 d ⊙ (A @ U1) - T0;  Tb2, UTa = d*T2
  cheb_mm_kernel<<<512, 256, 0, stream>>>(Abf, UTb, dv, Tb, Tb + 2 * TBE, UTa, 2.0f);
  // T3 = 2 d ⊙ (A @ U2) - T1;  Tb3
  cheb_mm_kernel<<<512, 256, 0, stream>>>(Abf, UTa, dv, Tb + TBE, Tb + 3 * TBE, nullptr, 2.0f);
  final_gemm_kernel<<<512, 256, 0, stream>>>(Tb, WT, bias, out);
}

// Round 5
// 137.181 us; speedup vs baseline: 1.5207x; 1.1239x over previous
//
#include <hip/hip_runtime.h>

typedef __attribute__((ext_vector_type(4))) float  f32x4;
typedef __attribute__((ext_vector_type(8))) short  bf16x8;
typedef __attribute__((ext_vector_type(4))) int    i32x4;
typedef __attribute__((ext_vector_type(4))) unsigned short u16x4;
typedef __attribute__((ext_vector_type(8))) unsigned short u16x8;

#define NB 16      // batch
#define NN 2048    // nodes
#define FF 64      // features

// combined dequant scale: A scale 127, U fixed-point scale 2^17
#define INV_SCALE (1.0f / (127.0f * 131072.0f))

// round-to-nearest-even f32 -> bf16 bits
__device__ __forceinline__ unsigned short f2bf(float x) {
  union { float f; unsigned int u; } c; c.f = x;
  unsigned int u = c.u;
  return (unsigned short)((u + 0x7fffu + ((u >> 16) & 1u)) >> 16);
}
__device__ __forceinline__ float bf2f(unsigned short b) {
  union { unsigned int u; float f; } c; c.u = (unsigned int)b << 16;
  return c.f;
}

__device__ __forceinline__ void gload16(const void* g, void* l) {
  __builtin_amdgcn_global_load_lds(
      (const __attribute__((address_space(1))) void*)g,
      (__attribute__((address_space(3))) void*)l, 16, 0, 0);
}

#define BAR() asm volatile("s_barrier" ::: "memory")

// Pass 1: one wave per row. rowsum (diag excluded, f32 exact) ->
// d = 1/(eps+sqrt(s)); A -> i8 (round(A*127)) with diag zeroed.
// NT read on A (read exactly once) so the freshly written A8 stays in L3.
__global__ __launch_bounds__(256) void rowsum_conv_kernel(
    const float* __restrict__ A, char* __restrict__ A8,
    float* __restrict__ dvec) {
  int row = blockIdx.x * 4 + (threadIdx.x >> 6);
  int lane = threadIdx.x & 63;
  int i = row & (NN - 1);
  const float* arow = A + (size_t)row * NN;
  char* orow = A8 + (size_t)row * NN;
  float s = 0.f;
#pragma unroll
  for (int p = 0; p < 8; ++p) {
    int base = p * 256 + lane * 4;
    f32x4 v = __builtin_nontemporal_load((const f32x4*)(arow + base));
#pragma unroll
    for (int jj = 0; jj < 4; ++jj) if (base + jj == i) v[jj] = 0.f;
    s += v[0] + v[1] + v[2] + v[3];
    unsigned int q0 = (unsigned int)(int)rintf(v[0] * 127.f);
    unsigned int q1 = (unsigned int)(int)rintf(v[1] * 127.f);
    unsigned int q2 = (unsigned int)(int)rintf(v[2] * 127.f);
    unsigned int q3 = (unsigned int)(int)rintf(v[3] * 127.f);
    unsigned int w8 = (q0 & 255u) | ((q1 & 255u) << 8) |
                      ((q2 & 255u) << 16) | ((q3 & 255u) << 24);
    *(unsigned int*)(orow + base) = w8;
  }
#pragma unroll
  for (int off = 32; off > 0; off >>= 1) s += __shfl_down(s, off, 64);
  if (lane == 0) dvec[row] = 1.0f / (1e-6f + sqrtf(s));
}

// blocks 0..511: U planes from X:  Q = rint(d*X*2^17); Uh=Q>>7, Ul=Q&127;
//                Tb[b][n][f] = bf16(X)
// blocks 512..639: WT[c][k] = bf16(Kr[k][c])
__global__ __launch_bounds__(256) void scale_transpose_kernel(
    const float* __restrict__ V, const float* __restrict__ dvec,
    char* __restrict__ Uh, char* __restrict__ Ul,
    unsigned short* __restrict__ Tb,
    const float* __restrict__ Kr, unsigned short* __restrict__ WT) {
  int bid = blockIdx.x;
  int tid = threadIdx.x;
  if (bid >= 512) {
    int idx = (bid - 512) * 256 + tid;     // < 32768
    int k = idx >> 7, c = idx & 127;
    WT[c * 256 + k] = f2bf(Kr[idx]);
    return;
  }
  int b = bid >> 5;
  int n0 = (bid & 31) * 64;
  __shared__ float t[64][65];
#pragma unroll
  for (int it = 0; it < 4; ++it) {
    int e = it * 256 + tid;                // 1024 groups of 4 elements
    int nl = e >> 4;
    int f0 = (e & 15) * 4;
    int n = n0 + nl;
    f32x4 v = *(const f32x4*)&V[((size_t)b * NN + n) * FF + f0];
    float dd = dvec[b * NN + n];
    u16x4 o;
#pragma unroll
    for (int j = 0; j < 4; ++j) { o[j] = f2bf(v[j]); t[f0 + j][nl] = v[j] * dd; }
    *(u16x4*)&Tb[((size_t)b * NN + n) * FF + f0] = o;
  }
  __syncthreads();
#pragma unroll
  for (int it = 0; it < 2; ++it) {
    int c = it * 256 + tid;                // 512 groups of 8
    int f = c >> 3, nl0 = (c & 7) * 8;
    unsigned long long ph = 0, pl = 0;
#pragma unroll
    for (int j = 0; j < 8; ++j) {
      int q = (int)rintf(t[f][nl0 + j] * 131072.f);
      q = q > 16383 ? 16383 : (q < -16383 ? -16383 : q);
      ph |= (unsigned long long)((unsigned int)(q >> 7) & 255u) << (8 * j);
      pl |= (unsigned long long)((unsigned int)(q & 127)) << (8 * j);
    }
    size_t o = ((size_t)b * FF + f) * NN + n0 + nl0;
    *(unsigned long long*)&Uh[o] = ph;
    *(unsigned long long*)&Ul[o] = pl;
  }
}

// C = A8[b] (64 x 2048) @ U (2048 x 64) in dual-plane i8:
//   C_int = 128*(A8@Uh) + A8@Ul  (two exact i32 MFMA accumulators)
//   v = cs * d[n] * C_int - prevb[n][f](bf16)   (cs includes 1/(127*2^17))
//   Tbout = bf16(v); Uh/Ulout = planes of rint(d*v*2^17), transposed via LDS.
// K-tile 64 (64 B rows, 4x16B slots, XOR swizzle slot^(row&3)); 3-deep LDS
// pipeline with counted vmcnt; raw s_barrier. XCD swizzle: batches {2x,2x+1}
// pinned to XCD x (bid%8) for L2 residency of U/A8 panels.
__global__ __launch_bounds__(256) void cheb_mm_kernel(
    const char* __restrict__ A8,
    const char* __restrict__ Uh,
    const char* __restrict__ Ul,
    const float* __restrict__ dvec,
    const unsigned short* __restrict__ prevb,   // nullable
    unsigned short* __restrict__ Tbout,
    char* __restrict__ Uhout,                   // nullable
    char* __restrict__ Ulout,
    float cs) {
  __shared__ char lds[36864];  // A: 3x4096 @0; Uh: 3x4096 @12288; Ul: 3x4096 @24576
  int bid = blockIdx.x;
  int slot = bid >> 3;
  int b = (bid & 7) * 2 + (slot >> 5);
  int tm = slot & 31;
  int tid = threadIdx.x;
  int lane = tid & 63;
  int w = tid >> 6;
  int wm = w >> 1, wn = w & 1;
  int lr = lane >> 2;                  // local row 0..15 within 16-row chunk
  int gs = (lane & 3) ^ (lr & 3);      // inverse-swizzled source slot (16B)
  int r16 = lane & 15, kq = lane >> 4;
  const int NT = NN / 64;              // 32 k-steps

  const size_t abase = ((size_t)b * NN + (size_t)tm * 64) * NN;
  const size_t ubase = (size_t)b * FF * NN;

  i32x4 ach[2][2] = {};   // A @ Uh
  i32x4 acl[2][2] = {};   // A @ Ul

  auto stage = [&](int s, int kt) {    // 3 gload16 per wave
    int k0 = kt * 64;
    int r = w * 16 + lr;
    gload16(A8 + abase + (size_t)r * NN + k0 + gs * 16,
            &lds[s * 4096 + w * 1024]);
    gload16(Uh + ubase + (size_t)r * NN + k0 + gs * 16,
            &lds[12288 + s * 4096 + w * 1024]);
    gload16(Ul + ubase + (size_t)r * NN + k0 + gs * 16,
            &lds[24576 + s * 4096 + w * 1024]);
  };

  stage(0, 0); stage(1, 1); stage(2, 2);
  int s = 0;
  for (int t = 0; t < NT; ++t) {
    if (t < NT - 2)       asm volatile("s_waitcnt vmcnt(6)" ::: "memory");
    else if (t == NT - 2) asm volatile("s_waitcnt vmcnt(3)" ::: "memory");
    else                  asm volatile("s_waitcnt vmcnt(0)" ::: "memory");
    BAR();                                  // buf s ready for all waves
    i32x4 af[2], uhf[2], ulf[2];
#pragma unroll
    for (int mi = 0; mi < 2; ++mi) {
      int row = wm * 32 + mi * 16 + r16;
      af[mi] = *(const i32x4*)&lds[s * 4096 + row * 64 + ((kq ^ (row & 3)) * 16)];
    }
#pragma unroll
    for (int ni = 0; ni < 2; ++ni) {
      int fr = wn * 32 + ni * 16 + r16;
      uhf[ni] = *(const i32x4*)&lds[12288 + s * 4096 + fr * 64 + ((kq ^ (fr & 3)) * 16)];
      ulf[ni] = *(const i32x4*)&lds[24576 + s * 4096 + fr * 64 + ((kq ^ (fr & 3)) * 16)];
    }
#pragma unroll
    for (int mi = 0; mi < 2; ++mi)
#pragma unroll
      for (int ni = 0; ni < 2; ++ni) {
        ach[mi][ni] = __builtin_amdgcn_mfma_i32_16x16x64_i8(
            af[mi], uhf[ni], ach[mi][ni], 0, 0, 0);
        acl[mi][ni] = __builtin_amdgcn_mfma_i32_16x16x64_i8(
            af[mi], ulf[ni], acl[mi][ni], 0, 0, 0);
      }
    BAR();                                  // all waves done reading buf s
    if (t + 3 < NT) stage(s, t + 3);
    s = (s == 2) ? 0 : s + 1;
  }

  // epilogue: D mapping col=lane&15, row=(lane>>4)*4+r (dtype-independent)
  char (*th)[72]  = (char(*)[72])lds;            // 64x72 bytes @0
  char (*tlo)[72] = (char(*)[72])&lds[12288];    // 64x72 bytes @12288
  int n0 = tm * 64;
#pragma unroll
  for (int mi = 0; mi < 2; ++mi) {
#pragma unroll
    for (int r = 0; r < 4; ++r) {
      int rl = wm * 32 + mi * 16 + kq * 4 + r;
      int row = n0 + rl;
      float dd = dvec[b * NN + row];
      float dcs = dd * cs;
#pragma unroll
      for (int ni = 0; ni < 2; ++ni) {
        int col = wn * 32 + ni * 16 + r16;
        size_t idx = ((size_t)b * NN + row) * FF + col;
        float c = 128.f * (float)ach[mi][ni][r] + (float)acl[mi][ni][r];
        float v = dcs * c;
        if (prevb) v -= bf2f(prevb[idx]);
        Tbout[idx] = f2bf(v);
        if (Uhout) {
          int q = (int)rintf(dd * v * 131072.f);
          q = q > 16383 ? 16383 : (q < -16383 ? -16383 : q);
          th[col][rl]  = (char)(q >> 7);
          tlo[col][rl] = (char)(q & 127);
        }
      }
    }
  }
  if (Uhout) {
    __syncthreads();
#pragma unroll
    for (int it = 0; it < 2; ++it) {
      int c = tid + it * 256;
      int f = c >> 3, nl0 = (c & 7) * 8;
      unsigned long long vh = *(const unsigned long long*)&th[f][nl0];
      unsigned long long vl = *(const unsigned long long*)&tlo[f][nl0];
      size_t o = ((size_t)b * FF + f) * NN + n0 + nl0;
      *(unsigned long long*)&Uhout[o] = vh;
      *(unsigned long long*)&Ulout[o] = vl;
    }
  }
}

// out[m][c] = relu( sum_k Z[m][k]*W[k][c] + bias[c] ), Z = [Tb0|Tb1|Tb2|Tb3]
// BM=64, BN=128, BK=64; 4 waves (2x2), wave tile 32x64; 3-deep counted-vmcnt.
__global__ __launch_bounds__(256) void final_gemm_kernel(
    const unsigned short* __restrict__ Tb,   // [4][M][64] bf16
    const unsigned short* __restrict__ WT,   // [128][256] bf16
    const float* __restrict__ bias,
    float* __restrict__ out) {
  __shared__ unsigned short lds[36864];   // A: 3 x 4096 at 0; B: 3 x 8192 at 12288
  const int M = NB * NN;
  int m0 = blockIdx.x * 64;
  int tid = threadIdx.x;
  int lane = tid & 63, w = tid >> 6;
  int wm = w >> 1, wn = w & 1;
  int lr = lane >> 3, gs = (lane & 7) ^ lr;
  int r16 = lane & 15, kq = lane >> 4;

  f32x4 acc[2][4] = {};

  auto stage = [&](int s, int kt) {   // 6 gload16 per wave
    const unsigned short* asrc = Tb + (size_t)kt * M * FF;
#pragma unroll
    for (int i = 0; i < 2; ++i) {
      int chunk = w * 2 + i;                   // 8 chunks: 64 rows
      int r = chunk * 8 + lr;
      gload16(asrc + (size_t)(m0 + r) * FF + gs * 8,
              &lds[s * 4096 + chunk * 512]);
    }
#pragma unroll
    for (int i = 0; i < 4; ++i) {
      int chunk = w * 4 + i;                   // 16 chunks: 128 c-rows
      int c = chunk * 8 + lr;
      gload16(WT + c * 256 + kt * 64 + gs * 8,
              &lds[12288 + s * 8192 + chunk * 512]);
    }
  };

  stage(0, 0); stage(1, 1); stage(2, 2);
  int s = 0;
  for (int t = 0; t < 4; ++t) {
    if (t < 2)       asm volatile("s_waitcnt vmcnt(12)" ::: "memory");
    else if (t == 2) asm volatile("s_waitcnt vmcnt(6)" ::: "memory");
    else             asm volatile("s_waitcnt vmcnt(0)" ::: "memory");
    BAR();
    bf16x8 af[2][2], bfr[4][2];
#pragma unroll
    for (int ks = 0; ks < 2; ++ks) {
#pragma unroll
      for (int mi = 0; mi < 2; ++mi) {
        int row = wm * 32 + mi * 16 + r16;
        af[mi][ks] = *(const bf16x8*)&lds[s * 4096 + row * 64 +
                                          (((ks * 4 + kq) ^ (row & 7)) * 8)];
      }
#pragma unroll
      for (int ni = 0; ni < 4; ++ni) {
        int fr = wn * 64 + ni * 16 + r16;
        bfr[ni][ks] = *(const bf16x8*)&lds[12288 + s * 8192 + fr * 64 +
                                           (((ks * 4 + kq) ^ (fr & 7)) * 8)];
      }
    }
#pragma unroll
    for (int ks = 0; ks < 2; ++ks)
#pragma unroll
      for (int mi = 0; mi < 2; ++mi)
#pragma unroll
        for (int ni = 0; ni < 4; ++ni)
          acc[mi][ni] = __builtin_amdgcn_mfma_f32_16x16x32_bf16(
              af[mi][ks], bfr[ni][ks], acc[mi][ni], 0, 0, 0);
    BAR();
    if (t + 3 < 4) stage(s, t + 3);
    s = (s == 2) ? 0 : s + 1;
  }

#pragma unroll
  for (int mi = 0; mi < 2; ++mi) {
#pragma unroll
    for (int r = 0; r < 4; ++r) {
      int row = m0 + wm * 32 + mi * 16 + kq * 4 + r;
#pragma unroll
      for (int ni = 0; ni < 4; ++ni) {
        int col = wn * 64 + ni * 16 + r16;
        float v = acc[mi][ni][r] + bias[col];
        out[(size_t)row * 128 + col] = v > 0.f ? v : 0.f;
      }
    }
  }
}

extern "C" void kernel_launch(void* const* d_in, const int* in_sizes, int n_in,
                              void* d_out, int out_size, void* d_ws, size_t ws_size,
                              hipStream_t stream) {
  const float* X    = (const float*)d_in[0];   // [16,2048,64]
  const float* A    = (const float*)d_in[1];   // [16,2048,2048]
  const float* Kr   = (const float*)d_in[2];   // [256,128]
  const float* bias = (const float*)d_in[3];   // [128]
  float* out = (float*)d_out;
  char* ws = (char*)d_ws;

  const size_t SZ_A8 = (size_t)NB * NN * NN;       // 67 MB i8 A
  const size_t SZ_D  = (size_t)NB * NN * 4;
  const size_t SZ_U  = (size_t)NB * FF * NN;       // 2 MB per i8 U plane
  const size_t SZ_TB = (size_t)NB * NN * FF * 2;   // 4 MB per bf16 slab
  const size_t TBE   = (size_t)NB * NN * FF;       // elements per Tb slab

  char*           A8  = ws;
  float*          dv  = (float*)(ws + SZ_A8);
  char*           Uha = ws + SZ_A8 + SZ_D;
  char*           Ula = Uha + SZ_U;
  char*           Uhb = Ula + SZ_U;
  char*           Ulb = Uhb + SZ_U;
  unsigned short* Tb  = (unsigned short*)(Ulb + SZ_U);
  unsigned short* WT  = (unsigned short*)(Ulb + SZ_U + 4 * SZ_TB);

  rowsum_conv_kernel<<<NB * NN / 4, 256, 0, stream>>>(A, A8, dv);
  // T0 = X: U planes of d*X; Tb0 = bf16(X); blocks 512+ convert the weight
  scale_transpose_kernel<<<640, 256, 0, stream>>>(X, dv, Uha, Ula, Tb, Kr, WT);
  // T1 = d ⊙ (A @ U0);        Tb1, U planes b
  cheb_mm_kernel<<<512, 256, 0, stream>>>(A8, Uha, Ula, dv, nullptr,
                                          Tb + TBE, Uhb, Ulb, 1.0f * INV_SCALE);
  // T2 = 2 d ⊙ (A @ U1) - T0; Tb2, U planes a
  cheb_mm_kernel<<<512, 256, 0, stream>>>(A8, Uhb, Ulb, dv, Tb,
                                          Tb + 2 * TBE, Uha, Ula, 2.0f * INV_SCALE);
  // T3 = 2 d ⊙ (A @ U2) - T1; Tb3
  cheb_mm_kernel<<<512, 256, 0, stream>>>(A8, Uha, Ula, dv, Tb + TBE,
                                          Tb + 3 * TBE, nullptr, nullptr, 2.0f * INV_SCALE);
  final_gemm_kernel<<<512, 256, 0, stream>>>(Tb, WT, bias, out);
}